// Round 8
// baseline (190.201 us; speedup 1.0000x reference)
//
#include <hip/hip_runtime.h>
#include <hip/hip_bf16.h>

// LowRankAttention: kv = x @ Wkv^T ; S = routers @ kv^T * scale ; P = softmax(S)
// ; AO = P @ kv ; out = AO @ Wproj^T + bias.  All GEMMs bf16 MFMA (f32 accum).
// Shapes: bs=32 ns=512 seq=1024 H=8 d_r=64 d_model=256.

typedef __attribute__((ext_vector_type(8))) short short8;
typedef __attribute__((ext_vector_type(4))) short short4v;
typedef __attribute__((ext_vector_type(4))) float f32x4;
typedef __attribute__((ext_vector_type(4))) unsigned int uint4v;
typedef __attribute__((ext_vector_type(4))) unsigned short ushort4v;

__device__ inline unsigned short f2bf(float f) {
  unsigned int u = __float_as_uint(f);
  u += 0x7FFFu + ((u >> 16) & 1u);   // RNE
  return (unsigned short)(u >> 16);
}

__device__ __forceinline__ void async_copy16(unsigned short* lds, const unsigned short* g) {
  __builtin_amdgcn_global_load_lds(
      (const __attribute__((address_space(1))) unsigned int*)g,
      (__attribute__((address_space(3))) unsigned int*)lds,
      16, 0, 0);
}

__global__ __launch_bounds__(256) void cast_f32_bf16(const float* __restrict__ in,
                                                     unsigned short* __restrict__ out, int n4) {
  int i = blockIdx.x * 256 + threadIdx.x;
  if (i >= n4) return;
  float4 v = ((const float4*)in)[i];
  ushort4v w; w.x = f2bf(v.x); w.y = f2bf(v.y); w.z = f2bf(v.z); w.w = f2bf(v.w);
  ((ushort4v*)out)[i] = w;
}

// ============ 256x256 8-phase GEMM with in-wave read-prefetch pipeline ============
// 512 thr = 8 waves (2M x 4N); wave tile 128x64; BK=64 as two k-halves of 32.
// LDS: sA/sB [2 buf][2 khalf][256 x 32] bf16 = 128 KiB. gload_lds width-16 staging.
// Pipeline: phase p's fragment ds_reads are issued during phase p-1 (double-buffered
// frag regs aX/aY, bX/bY) so they overlap MFMA_{p-1}. Counted lgkmcnt per phase:
// P1:4 P2:8 P3:4 P4:8 (own frags older than the in-flight prefetch; DS retires in order).
// Region safety: reads of region R retire (per-wave lgkmcnt) before MFMA_{p}, which is
// before barrier_p; the stage overwriting R issues at phase >= p+1. Cross-tile P1
// prefetch sits AFTER the tile-end vmcnt(6) (retires (t-1).P2/P3 + t.P1 stages).
// Swizzle: slot s of row r -> s ^ ((r>>1)&3) both sides (bank-conflict 0, measured).
__global__ __launch_bounds__(512, 1) void gemm1_8phase(
    const unsigned short* __restrict__ A, const unsigned short* __restrict__ B,
    unsigned short* __restrict__ C, int lda, int ldb, int ldc, int K, int nWGn)
{
  __shared__ __align__(16) unsigned short sA[2][2][8192];
  __shared__ __align__(16) unsigned short sB[2][2][8192];

  const int tid = threadIdx.x;
  const int cpx = gridDim.x >> 3;
  const int swz = (blockIdx.x & 7) * cpx + (blockIdx.x >> 3);
  const int bn = swz % nWGn, bm = swz / nWGn;

  const int wave = tid >> 6, lane = tid & 63;
  const int wm = wave >> 2, wn = wave & 3;
  const int lr = lane & 15, ls = lane >> 4;
  const int lsw8 = (ls ^ ((lr >> 1) & 3)) * 8;   // swizzled read slot (shorts)

  const int r0 = tid >> 2;
  const int sl0 = (tid & 3) ^ ((tid >> 3) & 3);  // source pre-swizzle (row+128 identical)
  const unsigned short* gA = A + (long long)(bm * 256 + r0) * lda + sl0 * 8;
  const unsigned short* gB = B + (long long)(bn * 256 + r0) * ldb + sl0 * 8;
  const long long lda128 = (long long)128 * lda, ldb128 = (long long)128 * ldb;

#define STA(b_, k_, t_) { const unsigned short* g_ = gA + (t_) * 64 + (k_) * 32; \
    async_copy16(&sA[b_][k_][tid * 8], g_); \
    async_copy16(&sA[b_][k_][4096 + tid * 8], g_ + lda128); }
#define STB(b_, k_, t_) { const unsigned short* g_ = gB + (t_) * 64 + (k_) * 32; \
    async_copy16(&sB[b_][k_][tid * 8], g_); \
    async_copy16(&sB[b_][k_][4096 + tid * 8], g_ + ldb128); }
// fragment loads: 4 x ds_read_b128 each
#define LDA4(dst, b_, k_, mh_) { _Pragma("unroll") \
    for (int mi = 0; mi < 4; ++mi) \
      dst[mi] = *(const short8*)&sA[b_][k_][(wm * 128 + ((mh_) * 4 + mi) * 16 + lr) * 32 + lsw8]; }
#define LDB4(dst, b_, k_) { _Pragma("unroll") \
    for (int ni = 0; ni < 4; ++ni) \
      dst[ni] = *(const short8*)&sB[b_][k_][(wn * 64 + ni * 16 + lr) * 32 + lsw8]; }
#define MFMA16(ah, src_a, src_b) { _Pragma("unroll") \
    for (int mi = 0; mi < 4; ++mi) { _Pragma("unroll") \
      for (int ni = 0; ni < 4; ++ni) \
        acc[(ah) * 4 + mi][ni] = __builtin_amdgcn_mfma_f32_16x16x32_bf16(src_a[mi], src_b[ni], acc[(ah) * 4 + mi][ni], 0, 0, 0); } }
#define FENCE() __builtin_amdgcn_sched_barrier(0)

  f32x4 acc[8][4];
  #pragma unroll
  for (int mi = 0; mi < 8; ++mi)
    #pragma unroll
    for (int ni = 0; ni < 4; ++ni)
      acc[mi][ni] = f32x4{0.f, 0.f, 0.f, 0.f};

  const int KT = K >> 6;
  STB(0, 0, 0) STA(0, 0, 0) STB(0, 1, 0) STA(0, 1, 0)
  if (KT > 1) {
    STB(1, 0, 1) STA(1, 0, 1) STB(1, 1, 1)
    asm volatile("s_waitcnt vmcnt(6)" ::: "memory");
  } else {
    asm volatile("s_waitcnt vmcnt(0)" ::: "memory");
  }
  __builtin_amdgcn_s_barrier();
  FENCE();

  short8 aX[4], aY[4], bX[4], bY[4];
  LDA4(aX, 0, 0, 0)   // tile0 P1 A-frags (mh0, khalf0)
  LDB4(bX, 0, 0)      // tile0 B0-frags

  for (int t = 0; t < KT; ++t) {
    const int b = t & 1, nb = b ^ 1;
    const bool hasT1 = (t + 1) < KT, hasT2 = (t + 2) < KT;

    // ---- P1: MFMA(mh0,k0) [aX,bX]; prefetch P2's A (aY = A0 mh1) ----
    if (hasT1) { STA(nb, 1, t + 1) }
    LDA4(aY, b, 0, 1)
    asm volatile("s_waitcnt lgkmcnt(4)" ::: "memory");
    FENCE();
    __builtin_amdgcn_s_setprio(1);
    MFMA16(0, aX, bX)
    __builtin_amdgcn_s_setprio(0);
    __builtin_amdgcn_s_barrier();
    FENCE();

    // ---- P2: MFMA(mh1,k0) [aY,bX]; prefetch P3's A+B (aX = A1 mh0, bY = B1) ----
    if (hasT2) { STB(b, 0, t + 2) }
    LDA4(aX, b, 1, 0)
    LDB4(bY, b, 1)
    asm volatile("s_waitcnt lgkmcnt(8)" ::: "memory");
    FENCE();
    __builtin_amdgcn_s_setprio(1);
    MFMA16(1, aY, bX)
    __builtin_amdgcn_s_setprio(0);
    __builtin_amdgcn_s_barrier();
    FENCE();

    // ---- P3: MFMA(mh0,k1) [aX,bY]; prefetch P4's A (aY = A1 mh1) ----
    if (hasT2) { STA(b, 0, t + 2) }
    LDA4(aY, b, 1, 1)
    asm volatile("s_waitcnt lgkmcnt(4)" ::: "memory");
    FENCE();
    __builtin_amdgcn_s_setprio(1);
    MFMA16(0, aX, bY)
    __builtin_amdgcn_s_setprio(0);
    __builtin_amdgcn_s_barrier();
    FENCE();

    // ---- P4: MFMA(mh1,k1) [aY,bY]; vmcnt; cross-tile prefetch (aX,bX from nb) ----
    if (hasT2) { STB(b, 1, t + 2) }
    if (hasT1) {
      if (t == KT - 2) {
        asm volatile("s_waitcnt vmcnt(0)" ::: "memory");
      } else {
        asm volatile("s_waitcnt vmcnt(6)" ::: "memory");
      }
      LDA4(aX, nb, 0, 0)
      LDB4(bX, nb, 0)
      asm volatile("s_waitcnt lgkmcnt(8)" ::: "memory");
    } else {
      asm volatile("s_waitcnt lgkmcnt(0)" ::: "memory");
    }
    FENCE();
    __builtin_amdgcn_s_setprio(1);
    MFMA16(1, aY, bY)
    __builtin_amdgcn_s_setprio(0);
    __builtin_amdgcn_s_barrier();
    FENCE();
  }
#undef STA
#undef STB
#undef LDA4
#undef LDB4
#undef MFMA16
#undef FENCE

  #pragma unroll
  for (int mi = 0; mi < 8; ++mi) {
    #pragma unroll
    for (int ni = 0; ni < 4; ++ni) {
      int row = bm * 256 + wm * 128 + mi * 16 + ls * 4;
      int col = bn * 256 + wn * 64 + ni * 16 + lr;
      #pragma unroll
      for (int r = 0; r < 4; ++r)
        C[(long long)(row + r) * ldc + col] = f2bf(acc[mi][ni][r]);
    }
  }
}

// ---------------- reg-staged batched GEMM (score, PV, proj) ----------
template<int BM,int BN,int BK,int WM,int WN,bool TRANS_B,bool A_F32,bool OUT_BF16,bool DO_SCALE,bool DO_BIAS>
__global__ __launch_bounds__(256) void gemm_bt(
    const void* __restrict__ Av, const unsigned short* __restrict__ Bp,
    void* __restrict__ Cv, const float* __restrict__ bias,
    int lda, int ldb, int ldc, int K, int nWGn,
    long long strAo, long long strAi, long long strBo, long long strBi,
    long long strCo, long long strCi, int binner, float scale)
{
  constexpr int PADA = 8;
  constexpr int PADB = TRANS_B ? 4 : 8;
  constexpr int STRA = BK + PADA;
  constexpr int STRB = BK + PADB;
  constexpr int NWN = BN / WN;
  constexpr int MF = WM / 16, NF = WN / 16;
  __shared__ __align__(16) unsigned short lds_a[BM * STRA];
  __shared__ __align__(16) unsigned short lds_b[BN * STRB];

  const int tid = threadIdx.x;
  const int bn = blockIdx.x % nWGn;
  const int bm = blockIdx.x / nWGn;
  const int batch = blockIdx.y;
  const int bo = batch / binner, bi = batch % binner;

  const int wave = tid >> 6, lane = tid & 63;
  const int wm = wave / NWN, wn = wave % NWN;
  const int lr = lane & 15;
  const int lk = (lane >> 4) * 8;

  const long long abase = bo*strAo + bi*strAi + (long long)bm*BM*lda;
  const long long bbase = bo*strBo + bi*strBi;

  f32x4 acc[MF][NF];
  #pragma unroll
  for (int mi = 0; mi < MF; ++mi)
    #pragma unroll
    for (int ni = 0; ni < NF; ++ni)
      acc[mi][ni] = f32x4{0.f, 0.f, 0.f, 0.f};

  for (int k0 = 0; k0 < K; k0 += BK) {
    if constexpr (A_F32) {
      const float* Af = (const float*)Av + abase + k0;
      #pragma unroll
      for (int i = 0; i < BM*BK/1024; ++i) {
        int c = i*256 + tid;
        int r = c / (BK/4);
        int kc = (c % (BK/4)) * 4;
        float4 v = *(const float4*)(Af + (long long)r*lda + kc);
        ushort4v w; w.x=f2bf(v.x); w.y=f2bf(v.y); w.z=f2bf(v.z); w.w=f2bf(v.w);
        *(ushort4v*)&lds_a[r*STRA + kc] = w;
      }
    } else {
      const unsigned short* Ab2 = (const unsigned short*)Av + abase + k0;
      #pragma unroll
      for (int i = 0; i < BM*BK/2048; ++i) {
        int c = i*256 + tid;
        int r = c / (BK/8);
        int kc = (c % (BK/8)) * 8;
        *(uint4v*)&lds_a[r*STRA + kc] = *(const uint4v*)(Ab2 + (long long)r*lda + kc);
      }
    }
    if constexpr (!TRANS_B) {
      const unsigned short* Bb2 = Bp + bbase + (long long)bn*BN*ldb + k0;
      #pragma unroll
      for (int i = 0; i < BN*BK/2048; ++i) {
        int c = i*256 + tid;
        int r = c / (BK/8);
        int kc = (c % (BK/8)) * 8;
        *(uint4v*)&lds_b[r*STRB + kc] = *(const uint4v*)(Bb2 + (long long)r*ldb + kc);
      }
    } else {
      const unsigned short* Bb2 = Bp + bbase + (long long)k0*ldb + (long long)bn*BN;
      #pragma unroll
      for (int i = 0; i < BN*BK/2048; ++i) {
        int c = i*256 + tid;
        int kr = c / (BN/8);
        int nc = (c % (BN/8)) * 8;
        uint4v v = *(const uint4v*)(Bb2 + (long long)kr*ldb + nc);
        const unsigned short* pv = (const unsigned short*)&v;
        #pragma unroll
        for (int j = 0; j < 8; ++j) lds_b[(nc+j)*STRB + kr] = pv[j];
      }
    }
    __syncthreads();

    #pragma unroll
    for (int kk = 0; kk < BK/32; ++kk) {
      short8 af[MF]; short8 bfr[NF];
      #pragma unroll
      for (int mi = 0; mi < MF; ++mi)
        af[mi] = *(const short8*)&lds_a[(wm*WM + mi*16 + lr)*STRA + kk*32 + lk];
      #pragma unroll
      for (int ni = 0; ni < NF; ++ni) {
        if constexpr (TRANS_B) {
          int base = (wn*WN + ni*16 + lr)*STRB + kk*32 + lk;
          short4v lo = *(const short4v*)&lds_b[base];
          short4v hi = *(const short4v*)&lds_b[base + 4];
          short8 t; t[0]=lo[0]; t[1]=lo[1]; t[2]=lo[2]; t[3]=lo[3];
                    t[4]=hi[0]; t[5]=hi[1]; t[6]=hi[2]; t[7]=hi[3];
          bfr[ni] = t;
        } else {
          bfr[ni] = *(const short8*)&lds_b[(wn*WN + ni*16 + lr)*STRB + kk*32 + lk];
        }
      }
      #pragma unroll
      for (int mi = 0; mi < MF; ++mi)
        #pragma unroll
        for (int ni = 0; ni < NF; ++ni)
          acc[mi][ni] = __builtin_amdgcn_mfma_f32_16x16x32_bf16(af[mi], bfr[ni], acc[mi][ni], 0, 0, 0);
    }
    __syncthreads();
  }

  const long long cbase = bo*strCo + bi*strCi;
  const int cr0 = (lane >> 4) * 4;
  #pragma unroll
  for (int mi = 0; mi < MF; ++mi) {
    #pragma unroll
    for (int ni = 0; ni < NF; ++ni) {
      int row = bm*BM + wm*WM + mi*16 + cr0;
      int col = bn*BN + wn*WN + ni*16 + lr;
      float badd = DO_BIAS ? bias[col] : 0.f;
      #pragma unroll
      for (int r = 0; r < 4; ++r) {
        float x = acc[mi][ni][r];
        if constexpr (DO_SCALE) x *= scale;
        x += badd;
        long long addr = cbase + (long long)(row + r)*ldc + col;
        if constexpr (OUT_BF16) ((unsigned short*)Cv)[addr] = f2bf(x);
        else                    ((float*)Cv)[addr] = x;
      }
    }
  }
}

// softmax over rows of 512 f32, in place; also emit bf16 copy. 1 wave per row.
__global__ __launch_bounds__(256) void softmax_rows(float* __restrict__ sc,
                                                    unsigned short* __restrict__ P) {
  int row = blockIdx.x * 4 + (threadIdx.x >> 6);
  int lane = threadIdx.x & 63;
  float* rp = sc + (long long)row * 512 + lane * 8;
  float4 a = *(const float4*)rp;
  float4 b = *(const float4*)(rp + 4);
  float v[8] = {a.x, a.y, a.z, a.w, b.x, b.y, b.z, b.w};
  float m = v[0];
  #pragma unroll
  for (int i = 1; i < 8; ++i) m = fmaxf(m, v[i]);
  #pragma unroll
  for (int d = 1; d < 64; d <<= 1) m = fmaxf(m, __shfl_xor(m, d, 64));
  float s = 0.f;
  #pragma unroll
  for (int i = 0; i < 8; ++i) { v[i] = __expf(v[i] - m); s += v[i]; }
  #pragma unroll
  for (int d = 1; d < 64; d <<= 1) s += __shfl_xor(s, d, 64);
  float inv = 1.0f / s;
  #pragma unroll
  for (int i = 0; i < 8; ++i) v[i] *= inv;
  float4 oa = {v[0], v[1], v[2], v[3]}, ob = {v[4], v[5], v[6], v[7]};
  *(float4*)rp = oa; *(float4*)(rp + 4) = ob;
  unsigned short* pp = P + (long long)row * 512 + lane * 8;
  ushort4v w0, w1;
  w0.x=f2bf(v[0]); w0.y=f2bf(v[1]); w0.z=f2bf(v[2]); w0.w=f2bf(v[3]);
  w1.x=f2bf(v[4]); w1.y=f2bf(v[5]); w1.z=f2bf(v[6]); w1.w=f2bf(v[7]);
  *(ushort4v*)pp = w0; *(ushort4v*)(pp + 4) = w1;
}

extern "C" void kernel_launch(void* const* d_in, const int* in_sizes, int n_in,
                              void* d_out, int out_size, void* d_ws, size_t ws_size,
                              hipStream_t stream) {
  const float* x       = (const float*)d_in[0];   // (32,512,1024)
  const float* routers = (const float*)d_in[1];   // (8,64,256)
  const float* wkv     = (const float*)d_in[2];   // (2048,1024)
  const float* projw   = (const float*)d_in[3];   // (1024,2048)
  const float* pbias   = (const float*)d_in[4];   // (1024,)

  char* ws = (char*)d_ws;
  unsigned short* wkv_b   = (unsigned short*)(ws);                //  4,194,304 B
  unsigned short* projw_b = (unsigned short*)(ws +  4194304);     //  4,194,304 B
  unsigned short* kv_b    = (unsigned short*)(ws +  8388608);     // 67,108,864 B (16384 x 2048)
  // region R: xb lives here ONLY during GEMM1; afterwards routers_b + P_b + ao_b.
  unsigned short* xb        = (unsigned short*)(ws + 75497472);   // 33,554,432 B (16384 x 1024)
  unsigned short* routers_b = (unsigned short*)(ws + 75497472);   //    262,144 B
  unsigned short* P_b       = (unsigned short*)(ws + 75759616);   // 16,777,216 B (bh x 64 x 512)
  unsigned short* ao_b      = (unsigned short*)(ws + 92536832);   //  8,388,608 B (2048 x 2048)

  float* out0  = (float*)d_out;            // (32,64,1024)
  float* attnw = out0 + 2097152;           // (32,8,64,512) — f32 scores, softmaxed in place

  cast_f32_bf16<<<2048,  256, 0, stream>>>(wkv,   wkv_b,   524288);
  cast_f32_bf16<<<2048,  256, 0, stream>>>(projw, projw_b, 524288);
  cast_f32_bf16<<<16384, 256, 0, stream>>>(x,     xb,      4194304);

  // kv = x @ wkv^T : M=16384 N=2048 K=1024 -> bf16 kv_b ; grid 64x8 = 512 wgs
  gemm1_8phase<<<512, 512, 0, stream>>>(xb, wkv_b, kv_b, 1024, 1024, 2048, 1024, 8);

  cast_f32_bf16<<<128, 256, 0, stream>>>(routers, routers_b, 32768);

  // S[bh] = routers[h] @ kv[b,h]^T * 1/16 : M=64 N=512 K=256, batch=256, out f32 -> attnw
  gemm_bt<64,128,64,64,32,false,false,false,true,false><<<dim3(4,256), 256, 0, stream>>>(
      routers_b, kv_b, attnw, nullptr, 256, 2048, 512, 256, 4,
      0, 16384, 1048576, 256, 262144, 32768, 8, 0.0625f);

  softmax_rows<<<4096, 256, 0, stream>>>(attnw, P_b);

  // AO[bh] = P[bh] @ kv[b,h] : M=64 N=256 K=512, TRANS_B, out bf16 -> ao_b (b*64+r, h*256+d)
  gemm_bt<64,128,64,64,32,true,false,true,false,false><<<dim3(2,256), 256, 0, stream>>>(
      P_b, kv_b, ao_b, nullptr, 512, 2048, 2048, 512, 2,
      262144, 32768, 1048576, 256, 131072, 256, 8, 1.0f);

  // out = AO @ projw^T + bias : M=2048 N=1024 K=2048, out f32
  gemm_bt<64,128,64,64,32,false,false,false,false,true><<<dim3(256,1), 256, 0, stream>>>(
      ao_b, projw_b, out0, pbias, 2048, 2048, 1024, 2048, 8,
      0,0, 0,0, 0,0, 1, 1.0f);
}

// Round 9
// 171.022 us; speedup vs baseline: 1.1121x; 1.1121x over previous
//
#include <hip/hip_runtime.h>
#include <hip/hip_bf16.h>

// LowRankAttention: kv = x @ Wkv^T ; S = routers @ kv^T * scale ; P = softmax(S)
// ; AO = P @ kv ; out = AO @ Wproj^T + bias.  All GEMMs bf16 MFMA (f32 accum).
// Shapes: bs=32 ns=512 seq=1024 H=8 d_r=64 d_model=256.

typedef __attribute__((ext_vector_type(8))) short short8;
typedef __attribute__((ext_vector_type(4))) short short4v;
typedef __attribute__((ext_vector_type(4))) float f32x4;
typedef __attribute__((ext_vector_type(4))) unsigned int uint4v;
typedef __attribute__((ext_vector_type(4))) unsigned short ushort4v;

__device__ inline unsigned short f2bf(float f) {
  unsigned int u = __float_as_uint(f);
  u += 0x7FFFu + ((u >> 16) & 1u);   // RNE
  return (unsigned short)(u >> 16);
}

__device__ __forceinline__ void async_copy16(unsigned short* lds, const unsigned short* g) {
  __builtin_amdgcn_global_load_lds(
      (const __attribute__((address_space(1))) unsigned int*)g,
      (__attribute__((address_space(3))) unsigned int*)lds,
      16, 0, 0);
}

// one kernel casts wkv (524288 f4), projw (524288 f4), x (4194304 f4); boundaries
// are multiples of 256 so branches are block-uniform.
__global__ __launch_bounds__(256) void cast_all(
    const float* __restrict__ x, const float* __restrict__ wkv, const float* __restrict__ projw,
    unsigned short* __restrict__ xb, unsigned short* __restrict__ wkv_b,
    unsigned short* __restrict__ projw_b) {
  int i = blockIdx.x * 256 + threadIdx.x;
  const float* src; unsigned short* dst; int off;
  if (i < 524288)        { src = wkv;   dst = wkv_b;   off = i; }
  else if (i < 1048576)  { src = projw; dst = projw_b; off = i - 524288; }
  else                   { src = x;     dst = xb;      off = i - 1048576; }
  float4 v = ((const float4*)src)[off];
  ushort4v w; w.x = f2bf(v.x); w.y = f2bf(v.y); w.z = f2bf(v.z); w.w = f2bf(v.w);
  ((ushort4v*)dst)[off] = w;
}

// ============ 256x256 8-phase GEMM (round-7 proven version, 897 TF) ============
// 512 thr = 8 waves (2M x 4N); BK=64 as two k-halves of 32. LDS 128 KiB, gload_lds
// width-16, ONE barrier per phase, counted vmcnt(6) at tile end, both-sides swizzle
// (bank-conflict 0 measured). Do not re-pin the schedule (round-8 regression).
__global__ __launch_bounds__(512, 1) void gemm1_8phase(
    const unsigned short* __restrict__ A, const unsigned short* __restrict__ B,
    unsigned short* __restrict__ C, int lda, int ldb, int ldc, int K, int nWGn)
{
  __shared__ __align__(16) unsigned short sA[2][2][8192];
  __shared__ __align__(16) unsigned short sB[2][2][8192];

  const int tid = threadIdx.x;
  const int cpx = gridDim.x >> 3;
  const int swz = (blockIdx.x & 7) * cpx + (blockIdx.x >> 3);
  const int bn = swz % nWGn, bm = swz / nWGn;

  const int wave = tid >> 6, lane = tid & 63;
  const int wm = wave >> 2, wn = wave & 3;
  const int lr = lane & 15, ls = lane >> 4;
  const int lsw8 = (ls ^ ((lr >> 1) & 3)) * 8;

  const int r0 = tid >> 2;
  const int sl0 = (tid & 3) ^ ((tid >> 3) & 3);
  const unsigned short* gA = A + (long long)(bm * 256 + r0) * lda + sl0 * 8;
  const unsigned short* gB = B + (long long)(bn * 256 + r0) * ldb + sl0 * 8;
  const long long lda128 = (long long)128 * lda, ldb128 = (long long)128 * ldb;

#define STA(b_, k_, t_) { const unsigned short* g_ = gA + (t_) * 64 + (k_) * 32; \
    async_copy16(&sA[b_][k_][tid * 8], g_); \
    async_copy16(&sA[b_][k_][4096 + tid * 8], g_ + lda128); }
#define STB(b_, k_, t_) { const unsigned short* g_ = gB + (t_) * 64 + (k_) * 32; \
    async_copy16(&sB[b_][k_][tid * 8], g_); \
    async_copy16(&sB[b_][k_][4096 + tid * 8], g_ + ldb128); }

  f32x4 acc[8][4];
  #pragma unroll
  for (int mi = 0; mi < 8; ++mi)
    #pragma unroll
    for (int ni = 0; ni < 4; ++ni)
      acc[mi][ni] = f32x4{0.f, 0.f, 0.f, 0.f};

  const int KT = K >> 6;
  STB(0, 0, 0) STA(0, 0, 0) STB(0, 1, 0) STA(0, 1, 0)
  if (KT > 1) {
    STB(1, 0, 1) STA(1, 0, 1) STB(1, 1, 1)
    asm volatile("s_waitcnt vmcnt(6)" ::: "memory");
  } else {
    asm volatile("s_waitcnt vmcnt(0)" ::: "memory");
  }
  __builtin_amdgcn_s_barrier();
  __builtin_amdgcn_sched_barrier(0);

  for (int t = 0; t < KT; ++t) {
    const int b = t & 1, nb = b ^ 1;
    const bool hasT1 = (t + 1) < KT, hasT2 = (t + 2) < KT;
    short8 af[4], bf[4];

    // ---- P1: (mh=0, kk=0) ----
    #pragma unroll
    for (int mi = 0; mi < 4; ++mi)
      af[mi] = *(const short8*)&sA[b][0][(wm * 128 + mi * 16 + lr) * 32 + lsw8];
    #pragma unroll
    for (int ni = 0; ni < 4; ++ni)
      bf[ni] = *(const short8*)&sB[b][0][(wn * 64 + ni * 16 + lr) * 32 + lsw8];
    if (hasT1) { STA(nb, 1, t + 1) }
    __builtin_amdgcn_s_setprio(1);
    #pragma unroll
    for (int mi = 0; mi < 4; ++mi)
      #pragma unroll
      for (int ni = 0; ni < 4; ++ni)
        acc[mi][ni] = __builtin_amdgcn_mfma_f32_16x16x32_bf16(af[mi], bf[ni], acc[mi][ni], 0, 0, 0);
    __builtin_amdgcn_s_setprio(0);
    __builtin_amdgcn_s_barrier();

    // ---- P2: (mh=1, kk=0) ----
    #pragma unroll
    for (int mi = 0; mi < 4; ++mi)
      af[mi] = *(const short8*)&sA[b][0][(wm * 128 + (4 + mi) * 16 + lr) * 32 + lsw8];
    if (hasT2) { STB(b, 0, t + 2) }
    __builtin_amdgcn_s_setprio(1);
    #pragma unroll
    for (int mi = 0; mi < 4; ++mi)
      #pragma unroll
      for (int ni = 0; ni < 4; ++ni)
        acc[4 + mi][ni] = __builtin_amdgcn_mfma_f32_16x16x32_bf16(af[mi], bf[ni], acc[4 + mi][ni], 0, 0, 0);
    __builtin_amdgcn_s_setprio(0);
    __builtin_amdgcn_s_barrier();

    // ---- P3: (mh=0, kk=1) ----
    #pragma unroll
    for (int mi = 0; mi < 4; ++mi)
      af[mi] = *(const short8*)&sA[b][1][(wm * 128 + mi * 16 + lr) * 32 + lsw8];
    #pragma unroll
    for (int ni = 0; ni < 4; ++ni)
      bf[ni] = *(const short8*)&sB[b][1][(wn * 64 + ni * 16 + lr) * 32 + lsw8];
    if (hasT2) { STA(b, 0, t + 2) }
    __builtin_amdgcn_s_setprio(1);
    #pragma unroll
    for (int mi = 0; mi < 4; ++mi)
      #pragma unroll
      for (int ni = 0; ni < 4; ++ni)
        acc[mi][ni] = __builtin_amdgcn_mfma_f32_16x16x32_bf16(af[mi], bf[ni], acc[mi][ni], 0, 0, 0);
    __builtin_amdgcn_s_setprio(0);
    __builtin_amdgcn_s_barrier();

    // ---- P4: (mh=1, kk=1) ----
    #pragma unroll
    for (int mi = 0; mi < 4; ++mi)
      af[mi] = *(const short8*)&sA[b][1][(wm * 128 + (4 + mi) * 16 + lr) * 32 + lsw8];
    if (hasT2) { STB(b, 1, t + 2) }
    __builtin_amdgcn_s_setprio(1);
    #pragma unroll
    for (int mi = 0; mi < 4; ++mi)
      #pragma unroll
      for (int ni = 0; ni < 4; ++ni)
        acc[4 + mi][ni] = __builtin_amdgcn_mfma_f32_16x16x32_bf16(af[mi], bf[ni], acc[4 + mi][ni], 0, 0, 0);
    __builtin_amdgcn_s_setprio(0);
    if (t == KT - 2) {
      asm volatile("s_waitcnt vmcnt(0)" ::: "memory");
    } else if (t < KT - 2) {
      asm volatile("s_waitcnt vmcnt(6)" ::: "memory");
    }
    __builtin_amdgcn_s_barrier();
    __builtin_amdgcn_sched_barrier(0);
  }
#undef STA
#undef STB

  #pragma unroll
  for (int mi = 0; mi < 8; ++mi) {
    #pragma unroll
    for (int ni = 0; ni < 4; ++ni) {
      int row = bm * 256 + wm * 128 + mi * 16 + ls * 4;
      int col = bn * 256 + wn * 64 + ni * 16 + lr;
      #pragma unroll
      for (int r = 0; r < 4; ++r)
        C[(long long)(row + r) * ldc + col] = f2bf(acc[mi][ni][r]);
    }
  }
}

// ============ fused score+softmax: one wg per (b,h), 1024 thr / 16 waves ============
// S[64][512] = routers[h] @ kv[b,h]^T / 16 held in registers (acc[8] f32x4 per lane),
// row-softmax via 16-lane shfl_xor + LDS cross-wave reduce; writes attnw f32 + P bf16.
// Waves: wm = wave>>2 (rows wm*16..+15), wn = wave&3 (cols wn*128..+127).
__global__ __launch_bounds__(1024, 1) void score_softmax(
    const float* __restrict__ routers,      // f32 (8,64,256)
    const unsigned short* __restrict__ kv,  // (16384,2048): row b*512+n, col h*256+d
    float* __restrict__ attnw,              // (256,64,512) f32
    unsigned short* __restrict__ P)         // (256,64,512) bf16
{
  __shared__ __align__(16) unsigned short lds_a[64 * 72];
  __shared__ __align__(16) unsigned short lds_b[512 * 72];
  __shared__ float redmax[64][4];
  __shared__ float redsum[64][4];

  const int bh = blockIdx.x;
  const int b = bh >> 3, h = bh & 7;
  const int tid = threadIdx.x;
  const int wave = tid >> 6, lane = tid & 63;
  const int wm = wave >> 2, wn = wave & 3;
  const int lr = lane & 15, ls = lane >> 4;
  const int lk = ls * 8;

  const unsigned short* kvb = kv + (long long)b * 512 * 2048 + h * 256;
  const float* Rh = routers + h * 16384;

  f32x4 acc[8];
  #pragma unroll
  for (int ni = 0; ni < 8; ++ni) acc[ni] = f32x4{0.f, 0.f, 0.f, 0.f};

  for (int k0 = 0; k0 < 256; k0 += 64) {
    // stage A (64 x 64, f32 -> bf16): thread handles 4 floats
    {
      int r = tid >> 4, kc = (tid & 15) * 4;
      float4 v = *(const float4*)(Rh + r * 256 + k0 + kc);
      ushort4v w; w.x = f2bf(v.x); w.y = f2bf(v.y); w.z = f2bf(v.z); w.w = f2bf(v.w);
      *(ushort4v*)&lds_a[r * 72 + kc] = w;
    }
    // stage B (512 x 64 bf16): 4 x uint4v per thread
    #pragma unroll
    for (int i = 0; i < 4; ++i) {
      int c = i * 1024 + tid;
      int r = c >> 3, kc = (c & 7) * 8;
      *(uint4v*)&lds_b[r * 72 + kc] = *(const uint4v*)(kvb + (long long)r * 2048 + k0 + kc);
    }
    __syncthreads();
    #pragma unroll
    for (int kk = 0; kk < 2; ++kk) {
      short8 af = *(const short8*)&lds_a[(wm * 16 + lr) * 72 + kk * 32 + lk];
      #pragma unroll
      for (int ni = 0; ni < 8; ++ni) {
        short8 bf = *(const short8*)&lds_b[(wn * 128 + ni * 16 + lr) * 72 + kk * 32 + lk];
        acc[ni] = __builtin_amdgcn_mfma_f32_16x16x32_bf16(af, bf, acc[ni], 0, 0, 0);
      }
    }
    __syncthreads();
  }

  // ---- softmax: scale, row-max (16-lane shfl + cross-wave LDS), exp, sum, write ----
  #pragma unroll
  for (int q = 0; q < 4; ++q) {
    int row = wm * 16 + ls * 4 + q;
    float m = -1e30f;
    #pragma unroll
    for (int ni = 0; ni < 8; ++ni) { acc[ni][q] *= 0.0625f; m = fmaxf(m, acc[ni][q]); }
    #pragma unroll
    for (int d = 1; d < 16; d <<= 1) m = fmaxf(m, __shfl_xor(m, d, 64));
    if (lr == 0) redmax[row][wn] = m;
  }
  __syncthreads();
  #pragma unroll
  for (int q = 0; q < 4; ++q) {
    int row = wm * 16 + ls * 4 + q;
    float M = fmaxf(fmaxf(redmax[row][0], redmax[row][1]), fmaxf(redmax[row][2], redmax[row][3]));
    float s = 0.f;
    #pragma unroll
    for (int ni = 0; ni < 8; ++ni) { float p = __expf(acc[ni][q] - M); acc[ni][q] = p; s += p; }
    #pragma unroll
    for (int d = 1; d < 16; d <<= 1) s += __shfl_xor(s, d, 64);
    if (lr == 0) redsum[row][wn] = s;
  }
  __syncthreads();
  #pragma unroll
  for (int q = 0; q < 4; ++q) {
    int row = wm * 16 + ls * 4 + q;
    float inv = 1.0f / (redsum[row][0] + redsum[row][1] + redsum[row][2] + redsum[row][3]);
    long long base = (long long)bh * 32768 + row * 512 + wn * 128;
    #pragma unroll
    for (int ni = 0; ni < 8; ++ni) {
      float wv = acc[ni][q] * inv;
      attnw[base + ni * 16 + lr] = wv;
      P[base + ni * 16 + lr] = f2bf(wv);
    }
  }
}

// ---------------- reg-staged batched GEMM (PV, proj) ----------
template<int BM,int BN,int BK,int WM,int WN,bool TRANS_B,bool A_F32,bool OUT_BF16,bool DO_SCALE,bool DO_BIAS>
__global__ __launch_bounds__(256) void gemm_bt(
    const void* __restrict__ Av, const unsigned short* __restrict__ Bp,
    void* __restrict__ Cv, const float* __restrict__ bias,
    int lda, int ldb, int ldc, int K, int nWGn,
    long long strAo, long long strAi, long long strBo, long long strBi,
    long long strCo, long long strCi, int binner, float scale)
{
  constexpr int PADA = 8;
  constexpr int PADB = TRANS_B ? 4 : 8;
  constexpr int STRA = BK + PADA;
  constexpr int STRB = BK + PADB;
  constexpr int NWN = BN / WN;
  constexpr int MF = WM / 16, NF = WN / 16;
  __shared__ __align__(16) unsigned short lds_a[BM * STRA];
  __shared__ __align__(16) unsigned short lds_b[BN * STRB];

  const int tid = threadIdx.x;
  const int bn = blockIdx.x % nWGn;
  const int bm = blockIdx.x / nWGn;
  const int batch = blockIdx.y;
  const int bo = batch / binner, bi = batch % binner;

  const int wave = tid >> 6, lane = tid & 63;
  const int wm = wave / NWN, wn = wave % NWN;
  const int lr = lane & 15;
  const int lk = (lane >> 4) * 8;

  const long long abase = bo*strAo + bi*strAi + (long long)bm*BM*lda;
  const long long bbase = bo*strBo + bi*strBi;

  f32x4 acc[MF][NF];
  #pragma unroll
  for (int mi = 0; mi < MF; ++mi)
    #pragma unroll
    for (int ni = 0; ni < NF; ++ni)
      acc[mi][ni] = f32x4{0.f, 0.f, 0.f, 0.f};

  for (int k0 = 0; k0 < K; k0 += BK) {
    if constexpr (A_F32) {
      const float* Af = (const float*)Av + abase + k0;
      #pragma unroll
      for (int i = 0; i < BM*BK/1024; ++i) {
        int c = i*256 + tid;
        int r = c / (BK/4);
        int kc = (c % (BK/4)) * 4;
        float4 v = *(const float4*)(Af + (long long)r*lda + kc);
        ushort4v w; w.x=f2bf(v.x); w.y=f2bf(v.y); w.z=f2bf(v.z); w.w=f2bf(v.w);
        *(ushort4v*)&lds_a[r*STRA + kc] = w;
      }
    } else {
      const unsigned short* Ab2 = (const unsigned short*)Av + abase + k0;
      #pragma unroll
      for (int i = 0; i < BM*BK/2048; ++i) {
        int c = i*256 + tid;
        int r = c / (BK/8);
        int kc = (c % (BK/8)) * 8;
        *(uint4v*)&lds_a[r*STRA + kc] = *(const uint4v*)(Ab2 + (long long)r*lda + kc);
      }
    }
    if constexpr (!TRANS_B) {
      const unsigned short* Bb2 = Bp + bbase + (long long)bn*BN*ldb + k0;
      #pragma unroll
      for (int i = 0; i < BN*BK/2048; ++i) {
        int c = i*256 + tid;
        int r = c / (BK/8);
        int kc = (c % (BK/8)) * 8;
        *(uint4v*)&lds_b[r*STRB + kc] = *(const uint4v*)(Bb2 + (long long)r*ldb + kc);
      }
    } else {
      const unsigned short* Bb2 = Bp + bbase + (long long)k0*ldb + (long long)bn*BN;
      #pragma unroll
      for (int i = 0; i < BN*BK/2048; ++i) {
        int c = i*256 + tid;
        int kr = c / (BN/8);
        int nc = (c % (BN/8)) * 8;
        uint4v v = *(const uint4v*)(Bb2 + (long long)kr*ldb + nc);
        const unsigned short* pv = (const unsigned short*)&v;
        #pragma unroll
        for (int j = 0; j < 8; ++j) lds_b[(nc+j)*STRB + kr] = pv[j];
      }
    }
    __syncthreads();

    #pragma unroll
    for (int kk = 0; kk < BK/32; ++kk) {
      short8 af[MF]; short8 bfr[NF];
      #pragma unroll
      for (int mi = 0; mi < MF; ++mi)
        af[mi] = *(const short8*)&lds_a[(wm*WM + mi*16 + lr)*STRA + kk*32 + lk];
      #pragma unroll
      for (int ni = 0; ni < NF; ++ni) {
        if constexpr (TRANS_B) {
          int base = (wn*WN + ni*16 + lr)*STRB + kk*32 + lk;
          short4v lo = *(const short4v*)&lds_b[base];
          short4v hi = *(const short4v*)&lds_b[base + 4];
          short8 t; t[0]=lo[0]; t[1]=lo[1]; t[2]=lo[2]; t[3]=lo[3];
                    t[4]=hi[0]; t[5]=hi[1]; t[6]=hi[2]; t[7]=hi[3];
          bfr[ni] = t;
        } else {
          bfr[ni] = *(const short8*)&lds_b[(wn*WN + ni*16 + lr)*STRB + kk*32 + lk];
        }
      }
      #pragma unroll
      for (int mi = 0; mi < MF; ++mi)
        #pragma unroll
        for (int ni = 0; ni < NF; ++ni)
          acc[mi][ni] = __builtin_amdgcn_mfma_f32_16x16x32_bf16(af[mi], bfr[ni], acc[mi][ni], 0, 0, 0);
    }
    __syncthreads();
  }

  const long long cbase = bo*strCo + bi*strCi;
  const int cr0 = (lane >> 4) * 4;
  #pragma unroll
  for (int mi = 0; mi < MF; ++mi) {
    #pragma unroll
    for (int ni = 0; ni < NF; ++ni) {
      int row = bm*BM + wm*WM + mi*16 + cr0;
      int col = bn*BN + wn*WN + ni*16 + lr;
      float badd = DO_BIAS ? bias[col] : 0.f;
      #pragma unroll
      for (int r = 0; r < 4; ++r) {
        float x = acc[mi][ni][r];
        if constexpr (DO_SCALE) x *= scale;
        x += badd;
        long long addr = cbase + (long long)(row + r)*ldc + col;
        if constexpr (OUT_BF16) ((unsigned short*)Cv)[addr] = f2bf(x);
        else                    ((float*)Cv)[addr] = x;
      }
    }
  }
}

extern "C" void kernel_launch(void* const* d_in, const int* in_sizes, int n_in,
                              void* d_out, int out_size, void* d_ws, size_t ws_size,
                              hipStream_t stream) {
  const float* x       = (const float*)d_in[0];   // (32,512,1024)
  const float* routers = (const float*)d_in[1];   // (8,64,256)
  const float* wkv     = (const float*)d_in[2];   // (2048,1024)
  const float* projw   = (const float*)d_in[3];   // (1024,2048)
  const float* pbias   = (const float*)d_in[4];   // (1024,)

  char* ws = (char*)d_ws;
  unsigned short* wkv_b   = (unsigned short*)(ws);                //  4,194,304 B
  unsigned short* projw_b = (unsigned short*)(ws +  4194304);     //  4,194,304 B
  unsigned short* kv_b    = (unsigned short*)(ws +  8388608);     // 67,108,864 B (16384 x 2048)
  // region R: xb lives here ONLY during gemm1; P_b/ao_b reuse it afterwards.
  unsigned short* xb      = (unsigned short*)(ws + 75497472);     // 33,554,432 B (16384 x 1024)
  unsigned short* P_b     = (unsigned short*)(ws + 75759616);     // 16,777,216 B (bh x 64 x 512)
  unsigned short* ao_b    = (unsigned short*)(ws + 92536832);     //  8,388,608 B (2048 x 2048)
  // total ws use: 100,925,440 B

  float* out0  = (float*)d_out;            // (32,64,1024)
  float* attnw = out0 + 2097152;           // (32,8,64,512) f32 softmax output

  // one cast kernel: wkv | projw | x  (5,242,880 float4 units)
  cast_all<<<20480, 256, 0, stream>>>(x, wkv, projw, xb, wkv_b, projw_b);

  // kv = x @ wkv^T : M=16384 N=2048 K=1024 -> bf16 kv_b ; grid 64x8 = 512 wgs
  gemm1_8phase<<<512, 512, 0, stream>>>(xb, wkv_b, kv_b, 1024, 1024, 2048, 1024, 8);

  // fused S = routers@kv^T/16 + row-softmax -> attnw (f32) + P_b (bf16); 1 wg per bh
  score_softmax<<<256, 1024, 0, stream>>>(routers, kv_b, attnw, P_b);

  // AO[bh] = P[bh] @ kv[b,h] : M=64 N=256 K=512, TRANS_B, out bf16 -> ao_b (b*64+r, h*256+d)
  gemm_bt<64,128,64,64,32,true,false,true,false,false><<<dim3(2,256), 256, 0, stream>>>(
      P_b, kv_b, ao_b, nullptr, 512, 2048, 2048, 512, 2,
      262144, 32768, 1048576, 256, 131072, 256, 8, 1.0f);

  // out = AO @ projw^T + bias : M=2048 N=1024 K=2048, out f32
  gemm_bt<64,128,64,64,32,false,false,false,false,true><<<dim3(256,1), 256, 0, stream>>>(
      ao_b, projw_b, out0, pbias, 2048, 2048, 1024, 2048, 8,
      0,0, 0,0, 0,0, 1, 1.0f);
}

// Round 10
// 163.152 us; speedup vs baseline: 1.1658x; 1.0482x over previous
//
#include <hip/hip_runtime.h>
#include <hip/hip_bf16.h>

// LowRankAttention: kv = x @ Wkv^T ; S = routers @ kv^T * scale ; P = softmax(S)
// ; AO = P @ kv ; out = AO @ Wproj^T + bias.  All GEMMs bf16 MFMA (f32 accum).
// Shapes: bs=32 ns=512 seq=1024 H=8 d_r=64 d_model=256.

typedef __attribute__((ext_vector_type(8))) short short8;
typedef __attribute__((ext_vector_type(4))) short short4v;
typedef __attribute__((ext_vector_type(4))) float f32x4;
typedef __attribute__((ext_vector_type(4))) unsigned int uint4v;
typedef __attribute__((ext_vector_type(4))) unsigned short ushort4v;

__device__ inline unsigned short f2bf(float f) {
  unsigned int u = __float_as_uint(f);
  u += 0x7FFFu + ((u >> 16) & 1u);   // RNE
  return (unsigned short)(u >> 16);
}

__device__ __forceinline__ void async_copy16(unsigned short* lds, const unsigned short* g) {
  __builtin_amdgcn_global_load_lds(
      (const __attribute__((address_space(1))) unsigned int*)g,
      (__attribute__((address_space(3))) unsigned int*)lds,
      16, 0, 0);
}

// one kernel casts wkv (524288 f4), projw (524288 f4), x (4194304 f4); boundaries
// are multiples of 256 so branches are block-uniform.
__global__ __launch_bounds__(256) void cast_all(
    const float* __restrict__ x, const float* __restrict__ wkv, const float* __restrict__ projw,
    unsigned short* __restrict__ xb, unsigned short* __restrict__ wkv_b,
    unsigned short* __restrict__ projw_b) {
  int i = blockIdx.x * 256 + threadIdx.x;
  const float* src; unsigned short* dst; int off;
  if (i < 524288)        { src = wkv;   dst = wkv_b;   off = i; }
  else if (i < 1048576)  { src = projw; dst = projw_b; off = i - 524288; }
  else                   { src = x;     dst = xb;      off = i - 1048576; }
  float4 v = ((const float4*)src)[off];
  ushort4v w; w.x = f2bf(v.x); w.y = f2bf(v.y); w.z = f2bf(v.z); w.w = f2bf(v.w);
  ((ushort4v*)dst)[off] = w;
}

// ============ 256x256 8-phase GEMM (round-7 proven version, ~900 TF) ============
// 512 thr = 8 waves (2M x 4N); BK=64 as two k-halves of 32. LDS 128 KiB, gload_lds
// width-16, ONE barrier per phase, counted vmcnt(6) at tile end, both-sides swizzle
// (bank-conflict 0 measured). Do not re-pin the schedule (round-8 regression).
__global__ __launch_bounds__(512, 1) void gemm1_8phase(
    const unsigned short* __restrict__ A, const unsigned short* __restrict__ B,
    unsigned short* __restrict__ C, int lda, int ldb, int ldc, int K, int nWGn)
{
  __shared__ __align__(16) unsigned short sA[2][2][8192];
  __shared__ __align__(16) unsigned short sB[2][2][8192];

  const int tid = threadIdx.x;
  const int cpx = gridDim.x >> 3;
  const int swz = (blockIdx.x & 7) * cpx + (blockIdx.x >> 3);
  const int bn = swz % nWGn, bm = swz / nWGn;

  const int wave = tid >> 6, lane = tid & 63;
  const int wm = wave >> 2, wn = wave & 3;
  const int lr = lane & 15, ls = lane >> 4;
  const int lsw8 = (ls ^ ((lr >> 1) & 3)) * 8;

  const int r0 = tid >> 2;
  const int sl0 = (tid & 3) ^ ((tid >> 3) & 3);
  const unsigned short* gA = A + (long long)(bm * 256 + r0) * lda + sl0 * 8;
  const unsigned short* gB = B + (long long)(bn * 256 + r0) * ldb + sl0 * 8;
  const long long lda128 = (long long)128 * lda, ldb128 = (long long)128 * ldb;

#define STA(b_, k_, t_) { const unsigned short* g_ = gA + (t_) * 64 + (k_) * 32; \
    async_copy16(&sA[b_][k_][tid * 8], g_); \
    async_copy16(&sA[b_][k_][4096 + tid * 8], g_ + lda128); }
#define STB(b_, k_, t_) { const unsigned short* g_ = gB + (t_) * 64 + (k_) * 32; \
    async_copy16(&sB[b_][k_][tid * 8], g_); \
    async_copy16(&sB[b_][k_][4096 + tid * 8], g_ + ldb128); }

  f32x4 acc[8][4];
  #pragma unroll
  for (int mi = 0; mi < 8; ++mi)
    #pragma unroll
    for (int ni = 0; ni < 4; ++ni)
      acc[mi][ni] = f32x4{0.f, 0.f, 0.f, 0.f};

  const int KT = K >> 6;
  STB(0, 0, 0) STA(0, 0, 0) STB(0, 1, 0) STA(0, 1, 0)
  if (KT > 1) {
    STB(1, 0, 1) STA(1, 0, 1) STB(1, 1, 1)
    asm volatile("s_waitcnt vmcnt(6)" ::: "memory");
  } else {
    asm volatile("s_waitcnt vmcnt(0)" ::: "memory");
  }
  __builtin_amdgcn_s_barrier();
  __builtin_amdgcn_sched_barrier(0);

  for (int t = 0; t < KT; ++t) {
    const int b = t & 1, nb = b ^ 1;
    const bool hasT1 = (t + 1) < KT, hasT2 = (t + 2) < KT;
    short8 af[4], bf[4];

    // ---- P1: (mh=0, kk=0) ----
    #pragma unroll
    for (int mi = 0; mi < 4; ++mi)
      af[mi] = *(const short8*)&sA[b][0][(wm * 128 + mi * 16 + lr) * 32 + lsw8];
    #pragma unroll
    for (int ni = 0; ni < 4; ++ni)
      bf[ni] = *(const short8*)&sB[b][0][(wn * 64 + ni * 16 + lr) * 32 + lsw8];
    if (hasT1) { STA(nb, 1, t + 1) }
    __builtin_amdgcn_s_setprio(1);
    #pragma unroll
    for (int mi = 0; mi < 4; ++mi)
      #pragma unroll
      for (int ni = 0; ni < 4; ++ni)
        acc[mi][ni] = __builtin_amdgcn_mfma_f32_16x16x32_bf16(af[mi], bf[ni], acc[mi][ni], 0, 0, 0);
    __builtin_amdgcn_s_setprio(0);
    __builtin_amdgcn_s_barrier();

    // ---- P2: (mh=1, kk=0) ----
    #pragma unroll
    for (int mi = 0; mi < 4; ++mi)
      af[mi] = *(const short8*)&sA[b][0][(wm * 128 + (4 + mi) * 16 + lr) * 32 + lsw8];
    if (hasT2) { STB(b, 0, t + 2) }
    __builtin_amdgcn_s_setprio(1);
    #pragma unroll
    for (int mi = 0; mi < 4; ++mi)
      #pragma unroll
      for (int ni = 0; ni < 4; ++ni)
        acc[4 + mi][ni] = __builtin_amdgcn_mfma_f32_16x16x32_bf16(af[mi], bf[ni], acc[4 + mi][ni], 0, 0, 0);
    __builtin_amdgcn_s_setprio(0);
    __builtin_amdgcn_s_barrier();

    // ---- P3: (mh=0, kk=1) ----
    #pragma unroll
    for (int mi = 0; mi < 4; ++mi)
      af[mi] = *(const short8*)&sA[b][1][(wm * 128 + mi * 16 + lr) * 32 + lsw8];
    #pragma unroll
    for (int ni = 0; ni < 4; ++ni)
      bf[ni] = *(const short8*)&sB[b][1][(wn * 64 + ni * 16 + lr) * 32 + lsw8];
    if (hasT2) { STA(b, 0, t + 2) }
    __builtin_amdgcn_s_setprio(1);
    #pragma unroll
    for (int mi = 0; mi < 4; ++mi)
      #pragma unroll
      for (int ni = 0; ni < 4; ++ni)
        acc[mi][ni] = __builtin_amdgcn_mfma_f32_16x16x32_bf16(af[mi], bf[ni], acc[mi][ni], 0, 0, 0);
    __builtin_amdgcn_s_setprio(0);
    __builtin_amdgcn_s_barrier();

    // ---- P4: (mh=1, kk=1) ----
    #pragma unroll
    for (int mi = 0; mi < 4; ++mi)
      af[mi] = *(const short8*)&sA[b][1][(wm * 128 + (4 + mi) * 16 + lr) * 32 + lsw8];
    if (hasT2) { STB(b, 1, t + 2) }
    __builtin_amdgcn_s_setprio(1);
    #pragma unroll
    for (int mi = 0; mi < 4; ++mi)
      #pragma unroll
      for (int ni = 0; ni < 4; ++ni)
        acc[4 + mi][ni] = __builtin_amdgcn_mfma_f32_16x16x32_bf16(af[mi], bf[ni], acc[4 + mi][ni], 0, 0, 0);
    __builtin_amdgcn_s_setprio(0);
    if (t == KT - 2) {
      asm volatile("s_waitcnt vmcnt(0)" ::: "memory");
    } else if (t < KT - 2) {
      asm volatile("s_waitcnt vmcnt(6)" ::: "memory");
    }
    __builtin_amdgcn_s_barrier();
    __builtin_amdgcn_sched_barrier(0);
  }
#undef STA
#undef STB

  #pragma unroll
  for (int mi = 0; mi < 8; ++mi) {
    #pragma unroll
    for (int ni = 0; ni < 4; ++ni) {
      int row = bm * 256 + wm * 128 + mi * 16 + ls * 4;
      int col = bn * 256 + wn * 64 + ni * 16 + lr;
      #pragma unroll
      for (int r = 0; r < 4; ++r)
        C[(long long)(row + r) * ldc + col] = f2bf(acc[mi][ni][r]);
    }
  }
}

// ======== fused score+softmax+PV: one wg per (b,h), 1024 thr / 16 waves ========
// Score: S[64][512] = routers[h] @ kv[b,h]^T / 16 in registers (acc[8] f32x4/lane).
// Softmax: 16-lane shfl + LDS cross-wave; writes attnw f32 + P bf16 into LDS
// (aliasing the dead kv score-staging region). PV: per 64-wide d-tile, transpose-
// stage kvT[64][512] in LDS (1024 thr, scalar writes conflict-free), then both
// operands are b128 reads; AO -> ao global. kv reads in PV are L2-hot from score.
// LDS carve (148 KiB): lds_a 9216 | lds_b 73728 (P aliases) | kvT 66560 | red 2048.
__global__ __launch_bounds__(1024, 1) void score_softmax_pv(
    const float* __restrict__ routers,      // f32 (8,64,256)
    const unsigned short* __restrict__ kv,  // (16384,2048): row b*512+n, col h*256+d
    float* __restrict__ attnw,              // (256,64,512) f32
    unsigned short* __restrict__ ao)        // (2048,2048): row b*64+r, col h*256+d
{
  __shared__ __align__(16) char smem[151552];
  unsigned short* lds_a = (unsigned short*)smem;                 // [64][72]
  unsigned short* lds_b = (unsigned short*)(smem + 9216);        // [512][72] kv tiles
  unsigned short* P_lds = (unsigned short*)(smem + 9216);        // [64][520] (aliases lds_b)
  unsigned short* kvT   = (unsigned short*)(smem + 82944);       // [64][520]
  float* redmax = (float*)(smem + 149504);                       // [64][4]
  float* redsum = (float*)(smem + 150528);                       // [64][4]

  const int bh = blockIdx.x;
  const int b = bh >> 3, h = bh & 7;
  const int tid = threadIdx.x;
  const int wave = tid >> 6, lane = tid & 63;
  const int wm = wave >> 2, wn = wave & 3;
  const int lr = lane & 15, ls = lane >> 4;
  const int lk = ls * 8;

  const unsigned short* kvb = kv + (long long)b * 512 * 2048 + h * 256;
  const float* Rh = routers + h * 16384;

  f32x4 acc[8];
  #pragma unroll
  for (int ni = 0; ni < 8; ++ni) acc[ni] = f32x4{0.f, 0.f, 0.f, 0.f};

  // ---- score: waves (wm: rows 16-block, wn: cols 128-block) ----
  for (int k0 = 0; k0 < 256; k0 += 64) {
    {
      int r = tid >> 4, kc = (tid & 15) * 4;
      float4 v = *(const float4*)(Rh + r * 256 + k0 + kc);
      ushort4v w; w.x = f2bf(v.x); w.y = f2bf(v.y); w.z = f2bf(v.z); w.w = f2bf(v.w);
      *(ushort4v*)&lds_a[r * 72 + kc] = w;
    }
    #pragma unroll
    for (int i = 0; i < 4; ++i) {
      int c = i * 1024 + tid;
      int r = c >> 3, kc = (c & 7) * 8;
      *(uint4v*)&lds_b[r * 72 + kc] = *(const uint4v*)(kvb + (long long)r * 2048 + k0 + kc);
    }
    __syncthreads();
    #pragma unroll
    for (int kk = 0; kk < 2; ++kk) {
      short8 af = *(const short8*)&lds_a[(wm * 16 + lr) * 72 + kk * 32 + lk];
      #pragma unroll
      for (int ni = 0; ni < 8; ++ni) {
        short8 bf = *(const short8*)&lds_b[(wn * 128 + ni * 16 + lr) * 72 + kk * 32 + lk];
        acc[ni] = __builtin_amdgcn_mfma_f32_16x16x32_bf16(af, bf, acc[ni], 0, 0, 0);
      }
    }
    __syncthreads();
  }

  // ---- softmax (rows wm*16+ls*4+q; 16-lane groups span cols via wn) ----
  #pragma unroll
  for (int q = 0; q < 4; ++q) {
    int row = wm * 16 + ls * 4 + q;
    float m = -1e30f;
    #pragma unroll
    for (int ni = 0; ni < 8; ++ni) { acc[ni][q] *= 0.0625f; m = fmaxf(m, acc[ni][q]); }
    #pragma unroll
    for (int d = 1; d < 16; d <<= 1) m = fmaxf(m, __shfl_xor(m, d, 64));
    if (lr == 0) redmax[row * 4 + wn] = m;
  }
  __syncthreads();
  #pragma unroll
  for (int q = 0; q < 4; ++q) {
    int row = wm * 16 + ls * 4 + q;
    float M = fmaxf(fmaxf(redmax[row * 4 + 0], redmax[row * 4 + 1]),
                    fmaxf(redmax[row * 4 + 2], redmax[row * 4 + 3]));
    float s = 0.f;
    #pragma unroll
    for (int ni = 0; ni < 8; ++ni) { float p = __expf(acc[ni][q] - M); acc[ni][q] = p; s += p; }
    #pragma unroll
    for (int d = 1; d < 16; d <<= 1) s += __shfl_xor(s, d, 64);
    if (lr == 0) redsum[row * 4 + wn] = s;
  }
  __syncthreads();
  #pragma unroll
  for (int q = 0; q < 4; ++q) {
    int row = wm * 16 + ls * 4 + q;
    float inv = 1.0f / (redsum[row * 4 + 0] + redsum[row * 4 + 1] +
                        redsum[row * 4 + 2] + redsum[row * 4 + 3]);
    long long base = (long long)bh * 32768 + row * 512 + wn * 128;
    #pragma unroll
    for (int ni = 0; ni < 8; ++ni) {
      float wv = acc[ni][q] * inv;
      attnw[base + ni * 16 + lr] = wv;
      P_lds[row * 520 + wn * 128 + ni * 16 + lr] = f2bf(wv);   // aliases dead lds_b
    }
  }

  // ---- PV: AO[r,d] = sum_n P[r,n]*kv[n,d]; 4 d-tiles of 64 ----
  for (int dt = 0; dt < 4; ++dt) {
    // transpose-stage kvT[d'][n] = kv[n][dt*64+d']
    #pragma unroll
    for (int i = 0; i < 4; ++i) {
      int c = i * 1024 + tid;
      int n = c & 511, dgrp = c >> 9;                     // dgrp 0..7
      uint4v v = *(const uint4v*)&kvb[(long long)n * 2048 + dt * 64 + dgrp * 8];
      const unsigned short* pv = (const unsigned short*)&v;
      #pragma unroll
      for (int j = 0; j < 8; ++j) kvT[(dgrp * 8 + j) * 520 + n] = pv[j];
    }
    __syncthreads();   // covers P_lds writes (dt==0) and kvT staging
    f32x4 accp = f32x4{0.f, 0.f, 0.f, 0.f};
    #pragma unroll
    for (int kk = 0; kk < 16; ++kk) {
      short8 af = *(const short8*)&P_lds[(wm * 16 + lr) * 520 + kk * 32 + lk];
      short8 bf = *(const short8*)&kvT[(wn * 16 + lr) * 520 + kk * 32 + lk];
      accp = __builtin_amdgcn_mfma_f32_16x16x32_bf16(af, bf, accp, 0, 0, 0);
    }
    #pragma unroll
    for (int q = 0; q < 4; ++q) {
      int r = wm * 16 + ls * 4 + q;
      ao[(long long)(b * 64 + r) * 2048 + h * 256 + dt * 64 + wn * 16 + lr] = f2bf(accp[q]);
    }
    __syncthreads();   // before next tile's kvT overwrite
  }
}

// ---------------- reg-staged GEMM (proj) ----------
template<int BM,int BN,int BK,int WM,int WN,bool TRANS_B,bool A_F32,bool OUT_BF16,bool DO_SCALE,bool DO_BIAS>
__global__ __launch_bounds__(256) void gemm_bt(
    const void* __restrict__ Av, const unsigned short* __restrict__ Bp,
    void* __restrict__ Cv, const float* __restrict__ bias,
    int lda, int ldb, int ldc, int K, int nWGn,
    long long strAo, long long strAi, long long strBo, long long strBi,
    long long strCo, long long strCi, int binner, float scale)
{
  constexpr int PADA = 8;
  constexpr int PADB = TRANS_B ? 4 : 8;
  constexpr int STRA = BK + PADA;
  constexpr int STRB = BK + PADB;
  constexpr int NWN = BN / WN;
  constexpr int MF = WM / 16, NF = WN / 16;
  __shared__ __align__(16) unsigned short lds_a[BM * STRA];
  __shared__ __align__(16) unsigned short lds_b[BN * STRB];

  const int tid = threadIdx.x;
  const int bn = blockIdx.x % nWGn;
  const int bm = blockIdx.x / nWGn;
  const int batch = blockIdx.y;
  const int bo = batch / binner, bi = batch % binner;

  const int wave = tid >> 6, lane = tid & 63;
  const int wm = wave / NWN, wn = wave % NWN;
  const int lr = lane & 15;
  const int lk = (lane >> 4) * 8;

  const long long abase = bo*strAo + bi*strAi + (long long)bm*BM*lda;
  const long long bbase = bo*strBo + bi*strBi;

  f32x4 acc[MF][NF];
  #pragma unroll
  for (int mi = 0; mi < MF; ++mi)
    #pragma unroll
    for (int ni = 0; ni < NF; ++ni)
      acc[mi][ni] = f32x4{0.f, 0.f, 0.f, 0.f};

  for (int k0 = 0; k0 < K; k0 += BK) {
    if constexpr (A_F32) {
      const float* Af = (const float*)Av + abase + k0;
      #pragma unroll
      for (int i = 0; i < BM*BK/1024; ++i) {
        int c = i*256 + tid;
        int r = c / (BK/4);
        int kc = (c % (BK/4)) * 4;
        float4 v = *(const float4*)(Af + (long long)r*lda + kc);
        ushort4v w; w.x=f2bf(v.x); w.y=f2bf(v.y); w.z=f2bf(v.z); w.w=f2bf(v.w);
        *(ushort4v*)&lds_a[r*STRA + kc] = w;
      }
    } else {
      const unsigned short* Ab2 = (const unsigned short*)Av + abase + k0;
      #pragma unroll
      for (int i = 0; i < BM*BK/2048; ++i) {
        int c = i*256 + tid;
        int r = c / (BK/8);
        int kc = (c % (BK/8)) * 8;
        *(uint4v*)&lds_a[r*STRA + kc] = *(const uint4v*)(Ab2 + (long long)r*lda + kc);
      }
    }
    if constexpr (!TRANS_B) {
      const unsigned short* Bb2 = Bp + bbase + (long long)bn*BN*ldb + k0;
      #pragma unroll
      for (int i = 0; i < BN*BK/2048; ++i) {
        int c = i*256 + tid;
        int r = c / (BK/8);
        int kc = (c % (BK/8)) * 8;
        *(uint4v*)&lds_b[r*STRB + kc] = *(const uint4v*)(Bb2 + (long long)r*ldb + kc);
      }
    } else {
      const unsigned short* Bb2 = Bp + bbase + (long long)k0*ldb + (long long)bn*BN;
      #pragma unroll
      for (int i = 0; i < BN*BK/2048; ++i) {
        int c = i*256 + tid;
        int kr = c / (BN/8);
        int nc = (c % (BN/8)) * 8;
        uint4v v = *(const uint4v*)(Bb2 + (long long)kr*ldb + nc);
        const unsigned short* pv = (const unsigned short*)&v;
        #pragma unroll
        for (int j = 0; j < 8; ++j) lds_b[(nc+j)*STRB + kr] = pv[j];
      }
    }
    __syncthreads();

    #pragma unroll
    for (int kk = 0; kk < BK/32; ++kk) {
      short8 af[MF]; short8 bfr[NF];
      #pragma unroll
      for (int mi = 0; mi < MF; ++mi)
        af[mi] = *(const short8*)&lds_a[(wm*WM + mi*16 + lr)*STRA + kk*32 + lk];
      #pragma unroll
      for (int ni = 0; ni < NF; ++ni) {
        if constexpr (TRANS_B) {
          int base = (wn*WN + ni*16 + lr)*STRB + kk*32 + lk;
          short4v lo = *(const short4v*)&lds_b[base];
          short4v hi = *(const short4v*)&lds_b[base + 4];
          short8 t; t[0]=lo[0]; t[1]=lo[1]; t[2]=lo[2]; t[3]=lo[3];
                    t[4]=hi[0]; t[5]=hi[1]; t[6]=hi[2]; t[7]=hi[3];
          bfr[ni] = t;
        } else {
          bfr[ni] = *(const short8*)&lds_b[(wn*WN + ni*16 + lr)*STRB + kk*32 + lk];
        }
      }
      #pragma unroll
      for (int mi = 0; mi < MF; ++mi)
        #pragma unroll
        for (int ni = 0; ni < NF; ++ni)
          acc[mi][ni] = __builtin_amdgcn_mfma_f32_16x16x32_bf16(af[mi], bfr[ni], acc[mi][ni], 0, 0, 0);
    }
    __syncthreads();
  }

  const long long cbase = bo*strCo + bi*strCi;
  const int cr0 = (lane >> 4) * 4;
  #pragma unroll
  for (int mi = 0; mi < MF; ++mi) {
    #pragma unroll
    for (int ni = 0; ni < NF; ++ni) {
      int row = bm*BM + wm*WM + mi*16 + cr0;
      int col = bn*BN + wn*WN + ni*16 + lr;
      float badd = DO_BIAS ? bias[col] : 0.f;
      #pragma unroll
      for (int r = 0; r < 4; ++r) {
        float x = acc[mi][ni][r];
        if constexpr (DO_SCALE) x *= scale;
        x += badd;
        long long addr = cbase + (long long)(row + r)*ldc + col;
        if constexpr (OUT_BF16) ((unsigned short*)Cv)[addr] = f2bf(x);
        else                    ((float*)Cv)[addr] = x;
      }
    }
  }
}

extern "C" void kernel_launch(void* const* d_in, const int* in_sizes, int n_in,
                              void* d_out, int out_size, void* d_ws, size_t ws_size,
                              hipStream_t stream) {
  const float* x       = (const float*)d_in[0];   // (32,512,1024)
  const float* routers = (const float*)d_in[1];   // (8,64,256)
  const float* wkv     = (const float*)d_in[2];   // (2048,1024)
  const float* projw   = (const float*)d_in[3];   // (1024,2048)
  const float* pbias   = (const float*)d_in[4];   // (1024,)

  char* ws = (char*)d_ws;
  unsigned short* wkv_b   = (unsigned short*)(ws);                //  4,194,304 B
  unsigned short* projw_b = (unsigned short*)(ws +  4194304);     //  4,194,304 B
  unsigned short* kv_b    = (unsigned short*)(ws +  8388608);     // 67,108,864 B (16384 x 2048)
  // region R: xb lives here ONLY during gemm1; ao_b reuses it afterwards.
  unsigned short* xb      = (unsigned short*)(ws + 75497472);     // 33,554,432 B (16384 x 1024)
  unsigned short* ao_b    = (unsigned short*)(ws + 92536832);     //  8,388,608 B (2048 x 2048)

  float* out0  = (float*)d_out;            // (32,64,1024)
  float* attnw = out0 + 2097152;           // (32,8,64,512) f32 softmax output

  // one cast kernel: wkv | projw | x  (5,242,880 float4 units)
  cast_all<<<20480, 256, 0, stream>>>(x, wkv, projw, xb, wkv_b, projw_b);

  // kv = x @ wkv^T : M=16384 N=2048 K=1024 -> bf16 kv_b ; grid 64x8 = 512 wgs
  gemm1_8phase<<<512, 512, 0, stream>>>(xb, wkv_b, kv_b, 1024, 1024, 2048, 1024, 8);

  // fused S = routers@kv^T/16 + softmax -> attnw, then AO = P@kv -> ao_b; 1 wg per bh
  score_softmax_pv<<<256, 1024, 0, stream>>>(routers, kv_b, attnw, ao_b);

  // out = AO @ projw^T + bias : M=2048 N=1024 K=2048, out f32
  gemm_bt<64,128,64,64,32,false,false,false,false,true><<<dim3(256,1), 256, 0, stream>>>(
      ao_b, projw_b, out0, pbias, 2048, 2048, 1024, 2048, 8,
      0,0, 0,0, 0,0, 1, 1.0f);
}

// Round 11
// 161.659 us; speedup vs baseline: 1.1766x; 1.0092x over previous
//
#include <hip/hip_runtime.h>
#include <hip/hip_bf16.h>

// LowRankAttention: kv = x @ Wkv^T ; S = routers @ kv^T * scale ; P = softmax(S)
// ; AO = P @ kv ; out = AO @ Wproj^T + bias.  All GEMMs bf16 MFMA (f32 accum).
// Shapes: bs=32 ns=512 seq=1024 H=8 d_r=64 d_model=256.

typedef __attribute__((ext_vector_type(8))) short short8;
typedef __attribute__((ext_vector_type(4))) short short4v;
typedef __attribute__((ext_vector_type(4))) float f32x4;
typedef __attribute__((ext_vector_type(4))) unsigned int uint4v;
typedef __attribute__((ext_vector_type(4))) unsigned short ushort4v;

__device__ inline unsigned short f2bf(float f) {
  unsigned int u = __float_as_uint(f);
  u += 0x7FFFu + ((u >> 16) & 1u);   // RNE
  return (unsigned short)(u >> 16);
}

__device__ __forceinline__ void async_copy16(unsigned short* lds, const unsigned short* g) {
  __builtin_amdgcn_global_load_lds(
      (const __attribute__((address_space(1))) unsigned int*)g,
      (__attribute__((address_space(3))) unsigned int*)lds,
      16, 0, 0);
}

// casts wkv (524288 f4) | projw (524288 f4) | x (4194304 f4) AND zeroes out0
// (524288 f4) — all boundaries are multiples of 256 so branches are block-uniform.
__global__ __launch_bounds__(256) void cast_all(
    const float* __restrict__ x, const float* __restrict__ wkv, const float* __restrict__ projw,
    unsigned short* __restrict__ xb, unsigned short* __restrict__ wkv_b,
    unsigned short* __restrict__ projw_b, float* __restrict__ out0) {
  int i = blockIdx.x * 256 + threadIdx.x;
  if (i >= 5242880) {                                   // zero out0 (proj accumulates)
    ((float4*)out0)[i - 5242880] = float4{0.f, 0.f, 0.f, 0.f};
    return;
  }
  const float* src; unsigned short* dst; int off;
  if (i < 524288)        { src = wkv;   dst = wkv_b;   off = i; }
  else if (i < 1048576)  { src = projw; dst = projw_b; off = i - 524288; }
  else                   { src = x;     dst = xb;      off = i - 1048576; }
  float4 v = ((const float4*)src)[off];
  ushort4v w; w.x = f2bf(v.x); w.y = f2bf(v.y); w.z = f2bf(v.z); w.w = f2bf(v.w);
  ((ushort4v*)dst)[off] = w;
}

// ============ 256x256 8-phase GEMM (round-7 proven version, ~900 TF) ============
// 512 thr = 8 waves (2M x 4N); BK=64 as two k-halves of 32. LDS 128 KiB, gload_lds
// width-16, ONE barrier per phase, counted vmcnt(6) at tile end, both-sides swizzle
// (bank-conflict 0 measured). Do not re-pin the schedule (round-8 regression).
__global__ __launch_bounds__(512, 1) void gemm1_8phase(
    const unsigned short* __restrict__ A, const unsigned short* __restrict__ B,
    unsigned short* __restrict__ C, int lda, int ldb, int ldc, int K, int nWGn)
{
  __shared__ __align__(16) unsigned short sA[2][2][8192];
  __shared__ __align__(16) unsigned short sB[2][2][8192];

  const int tid = threadIdx.x;
  const int cpx = gridDim.x >> 3;
  const int swz = (blockIdx.x & 7) * cpx + (blockIdx.x >> 3);
  const int bn = swz % nWGn, bm = swz / nWGn;

  const int wave = tid >> 6, lane = tid & 63;
  const int wm = wave >> 2, wn = wave & 3;
  const int lr = lane & 15, ls = lane >> 4;
  const int lsw8 = (ls ^ ((lr >> 1) & 3)) * 8;

  const int r0 = tid >> 2;
  const int sl0 = (tid & 3) ^ ((tid >> 3) & 3);
  const unsigned short* gA = A + (long long)(bm * 256 + r0) * lda + sl0 * 8;
  const unsigned short* gB = B + (long long)(bn * 256 + r0) * ldb + sl0 * 8;
  const long long lda128 = (long long)128 * lda, ldb128 = (long long)128 * ldb;

#define STA(b_, k_, t_) { const unsigned short* g_ = gA + (t_) * 64 + (k_) * 32; \
    async_copy16(&sA[b_][k_][tid * 8], g_); \
    async_copy16(&sA[b_][k_][4096 + tid * 8], g_ + lda128); }
#define STB(b_, k_, t_) { const unsigned short* g_ = gB + (t_) * 64 + (k_) * 32; \
    async_copy16(&sB[b_][k_][tid * 8], g_); \
    async_copy16(&sB[b_][k_][4096 + tid * 8], g_ + ldb128); }

  f32x4 acc[8][4];
  #pragma unroll
  for (int mi = 0; mi < 8; ++mi)
    #pragma unroll
    for (int ni = 0; ni < 4; ++ni)
      acc[mi][ni] = f32x4{0.f, 0.f, 0.f, 0.f};

  const int KT = K >> 6;
  STB(0, 0, 0) STA(0, 0, 0) STB(0, 1, 0) STA(0, 1, 0)
  if (KT > 1) {
    STB(1, 0, 1) STA(1, 0, 1) STB(1, 1, 1)
    asm volatile("s_waitcnt vmcnt(6)" ::: "memory");
  } else {
    asm volatile("s_waitcnt vmcnt(0)" ::: "memory");
  }
  __builtin_amdgcn_s_barrier();
  __builtin_amdgcn_sched_barrier(0);

  for (int t = 0; t < KT; ++t) {
    const int b = t & 1, nb = b ^ 1;
    const bool hasT1 = (t + 1) < KT, hasT2 = (t + 2) < KT;
    short8 af[4], bf[4];

    // ---- P1: (mh=0, kk=0) ----
    #pragma unroll
    for (int mi = 0; mi < 4; ++mi)
      af[mi] = *(const short8*)&sA[b][0][(wm * 128 + mi * 16 + lr) * 32 + lsw8];
    #pragma unroll
    for (int ni = 0; ni < 4; ++ni)
      bf[ni] = *(const short8*)&sB[b][0][(wn * 64 + ni * 16 + lr) * 32 + lsw8];
    if (hasT1) { STA(nb, 1, t + 1) }
    __builtin_amdgcn_s_setprio(1);
    #pragma unroll
    for (int mi = 0; mi < 4; ++mi)
      #pragma unroll
      for (int ni = 0; ni < 4; ++ni)
        acc[mi][ni] = __builtin_amdgcn_mfma_f32_16x16x32_bf16(af[mi], bf[ni], acc[mi][ni], 0, 0, 0);
    __builtin_amdgcn_s_setprio(0);
    __builtin_amdgcn_s_barrier();

    // ---- P2: (mh=1, kk=0) ----
    #pragma unroll
    for (int mi = 0; mi < 4; ++mi)
      af[mi] = *(const short8*)&sA[b][0][(wm * 128 + (4 + mi) * 16 + lr) * 32 + lsw8];
    if (hasT2) { STB(b, 0, t + 2) }
    __builtin_amdgcn_s_setprio(1);
    #pragma unroll
    for (int mi = 0; mi < 4; ++mi)
      #pragma unroll
      for (int ni = 0; ni < 4; ++ni)
        acc[4 + mi][ni] = __builtin_amdgcn_mfma_f32_16x16x32_bf16(af[mi], bf[ni], acc[4 + mi][ni], 0, 0, 0);
    __builtin_amdgcn_s_setprio(0);
    __builtin_amdgcn_s_barrier();

    // ---- P3: (mh=0, kk=1) ----
    #pragma unroll
    for (int mi = 0; mi < 4; ++mi)
      af[mi] = *(const short8*)&sA[b][1][(wm * 128 + mi * 16 + lr) * 32 + lsw8];
    #pragma unroll
    for (int ni = 0; ni < 4; ++ni)
      bf[ni] = *(const short8*)&sB[b][1][(wn * 64 + ni * 16 + lr) * 32 + lsw8];
    if (hasT2) { STA(b, 0, t + 2) }
    __builtin_amdgcn_s_setprio(1);
    #pragma unroll
    for (int mi = 0; mi < 4; ++mi)
      #pragma unroll
      for (int ni = 0; ni < 4; ++ni)
        acc[mi][ni] = __builtin_amdgcn_mfma_f32_16x16x32_bf16(af[mi], bf[ni], acc[mi][ni], 0, 0, 0);
    __builtin_amdgcn_s_setprio(0);
    __builtin_amdgcn_s_barrier();

    // ---- P4: (mh=1, kk=1) ----
    #pragma unroll
    for (int mi = 0; mi < 4; ++mi)
      af[mi] = *(const short8*)&sA[b][1][(wm * 128 + (4 + mi) * 16 + lr) * 32 + lsw8];
    if (hasT2) { STB(b, 1, t + 2) }
    __builtin_amdgcn_s_setprio(1);
    #pragma unroll
    for (int mi = 0; mi < 4; ++mi)
      #pragma unroll
      for (int ni = 0; ni < 4; ++ni)
        acc[4 + mi][ni] = __builtin_amdgcn_mfma_f32_16x16x32_bf16(af[mi], bf[ni], acc[4 + mi][ni], 0, 0, 0);
    __builtin_amdgcn_s_setprio(0);
    if (t == KT - 2) {
      asm volatile("s_waitcnt vmcnt(0)" ::: "memory");
    } else if (t < KT - 2) {
      asm volatile("s_waitcnt vmcnt(6)" ::: "memory");
    }
    __builtin_amdgcn_s_barrier();
    __builtin_amdgcn_sched_barrier(0);
  }
#undef STA
#undef STB

  #pragma unroll
  for (int mi = 0; mi < 8; ++mi) {
    #pragma unroll
    for (int ni = 0; ni < 4; ++ni) {
      int row = bm * 256 + wm * 128 + mi * 16 + ls * 4;
      int col = bn * 256 + wn * 64 + ni * 16 + lr;
      #pragma unroll
      for (int r = 0; r < 4; ++r)
        C[(long long)(row + r) * ldc + col] = f2bf(acc[mi][ni][r]);
    }
  }
}

// ======== fused score+softmax+PV: one wg per (b,h), 1024 thr / 16 waves ========
// (round-10 proven). LDS carve (148 KiB): lds_a 9216 | lds_b 73728 (P aliases) |
// kvT 66560 | red 2048.  kv reads in PV are L2-hot from score.
__global__ __launch_bounds__(1024, 1) void score_softmax_pv(
    const float* __restrict__ routers,      // f32 (8,64,256)
    const unsigned short* __restrict__ kv,  // (16384,2048): row b*512+n, col h*256+d
    float* __restrict__ attnw,              // (256,64,512) f32
    unsigned short* __restrict__ ao)        // (2048,2048): row b*64+r, col h*256+d
{
  __shared__ __align__(16) char smem[151552];
  unsigned short* lds_a = (unsigned short*)smem;                 // [64][72]
  unsigned short* lds_b = (unsigned short*)(smem + 9216);        // [512][72] kv tiles
  unsigned short* P_lds = (unsigned short*)(smem + 9216);        // [64][520] (aliases lds_b)
  unsigned short* kvT   = (unsigned short*)(smem + 82944);       // [64][520]
  float* redmax = (float*)(smem + 149504);                       // [64][4]
  float* redsum = (float*)(smem + 150528);                       // [64][4]

  const int bh = blockIdx.x;
  const int b = bh >> 3, h = bh & 7;
  const int tid = threadIdx.x;
  const int wave = tid >> 6, lane = tid & 63;
  const int wm = wave >> 2, wn = wave & 3;
  const int lr = lane & 15, ls = lane >> 4;
  const int lk = ls * 8;

  const unsigned short* kvb = kv + (long long)b * 512 * 2048 + h * 256;
  const float* Rh = routers + h * 16384;

  f32x4 acc[8];
  #pragma unroll
  for (int ni = 0; ni < 8; ++ni) acc[ni] = f32x4{0.f, 0.f, 0.f, 0.f};

  // ---- score ----
  for (int k0 = 0; k0 < 256; k0 += 64) {
    {
      int r = tid >> 4, kc = (tid & 15) * 4;
      float4 v = *(const float4*)(Rh + r * 256 + k0 + kc);
      ushort4v w; w.x = f2bf(v.x); w.y = f2bf(v.y); w.z = f2bf(v.z); w.w = f2bf(v.w);
      *(ushort4v*)&lds_a[r * 72 + kc] = w;
    }
    #pragma unroll
    for (int i = 0; i < 4; ++i) {
      int c = i * 1024 + tid;
      int r = c >> 3, kc = (c & 7) * 8;
      *(uint4v*)&lds_b[r * 72 + kc] = *(const uint4v*)(kvb + (long long)r * 2048 + k0 + kc);
    }
    __syncthreads();
    #pragma unroll
    for (int kk = 0; kk < 2; ++kk) {
      short8 af = *(const short8*)&lds_a[(wm * 16 + lr) * 72 + kk * 32 + lk];
      #pragma unroll
      for (int ni = 0; ni < 8; ++ni) {
        short8 bf = *(const short8*)&lds_b[(wn * 128 + ni * 16 + lr) * 72 + kk * 32 + lk];
        acc[ni] = __builtin_amdgcn_mfma_f32_16x16x32_bf16(af, bf, acc[ni], 0, 0, 0);
      }
    }
    __syncthreads();
  }

  // ---- softmax ----
  #pragma unroll
  for (int q = 0; q < 4; ++q) {
    int row = wm * 16 + ls * 4 + q;
    float m = -1e30f;
    #pragma unroll
    for (int ni = 0; ni < 8; ++ni) { acc[ni][q] *= 0.0625f; m = fmaxf(m, acc[ni][q]); }
    #pragma unroll
    for (int d = 1; d < 16; d <<= 1) m = fmaxf(m, __shfl_xor(m, d, 64));
    if (lr == 0) redmax[row * 4 + wn] = m;
  }
  __syncthreads();
  #pragma unroll
  for (int q = 0; q < 4; ++q) {
    int row = wm * 16 + ls * 4 + q;
    float M = fmaxf(fmaxf(redmax[row * 4 + 0], redmax[row * 4 + 1]),
                    fmaxf(redmax[row * 4 + 2], redmax[row * 4 + 3]));
    float s = 0.f;
    #pragma unroll
    for (int ni = 0; ni < 8; ++ni) { float p = __expf(acc[ni][q] - M); acc[ni][q] = p; s += p; }
    #pragma unroll
    for (int d = 1; d < 16; d <<= 1) s += __shfl_xor(s, d, 64);
    if (lr == 0) redsum[row * 4 + wn] = s;
  }
  __syncthreads();
  #pragma unroll
  for (int q = 0; q < 4; ++q) {
    int row = wm * 16 + ls * 4 + q;
    float inv = 1.0f / (redsum[row * 4 + 0] + redsum[row * 4 + 1] +
                        redsum[row * 4 + 2] + redsum[row * 4 + 3]);
    long long base = (long long)bh * 32768 + row * 512 + wn * 128;
    #pragma unroll
    for (int ni = 0; ni < 8; ++ni) {
      float wv = acc[ni][q] * inv;
      attnw[base + ni * 16 + lr] = wv;
      P_lds[row * 520 + wn * 128 + ni * 16 + lr] = f2bf(wv);   // aliases dead lds_b
    }
  }

  // ---- PV: 4 d-tiles of 64 ----
  for (int dt = 0; dt < 4; ++dt) {
    #pragma unroll
    for (int i = 0; i < 4; ++i) {
      int c = i * 1024 + tid;
      int n = c & 511, dgrp = c >> 9;
      uint4v v = *(const uint4v*)&kvb[(long long)n * 2048 + dt * 64 + dgrp * 8];
      const unsigned short* pv = (const unsigned short*)&v;
      #pragma unroll
      for (int j = 0; j < 8; ++j) kvT[(dgrp * 8 + j) * 520 + n] = pv[j];
    }
    __syncthreads();
    f32x4 accp = f32x4{0.f, 0.f, 0.f, 0.f};
    #pragma unroll
    for (int kk = 0; kk < 16; ++kk) {
      short8 af = *(const short8*)&P_lds[(wm * 16 + lr) * 520 + kk * 32 + lk];
      short8 bf = *(const short8*)&kvT[(wn * 16 + lr) * 520 + kk * 32 + lk];
      accp = __builtin_amdgcn_mfma_f32_16x16x32_bf16(af, bf, accp, 0, 0, 0);
    }
    #pragma unroll
    for (int q = 0; q < 4; ++q) {
      int r = wm * 16 + ls * 4 + q;
      ao[(long long)(b * 64 + r) * 2048 + h * 256 + dt * 64 + wn * 16 + lr] = f2bf(accp[q]);
    }
    __syncthreads();
  }
}

// ---------------- reg-staged GEMM (proj, split-K atomic) ----------
// C[m,n] += sum_k A[m,k]*B[n,k] over this block's K-slice (batch = K-split index).
// out0 is zeroed by cast_all; exactly 2 commutative f32 atomic adds per element
// (bias folded into the kp==0 partial) -> deterministic result.
template<int BM,int BN,int BK,int WM,int WN,bool DO_BIAS>
__global__ __launch_bounds__(256) void gemm_bt_splitk(
    const unsigned short* __restrict__ Ap, const unsigned short* __restrict__ Bp,
    float* __restrict__ Cv, const float* __restrict__ bias,
    int lda, int ldb, int ldc, int Kslice, int nWGn)
{
  constexpr int STRA = BK + 8;
  constexpr int STRB = BK + 8;
  constexpr int NWN = BN / WN;
  constexpr int MF = WM / 16, NF = WN / 16;
  __shared__ __align__(16) unsigned short lds_a[BM * STRA];
  __shared__ __align__(16) unsigned short lds_b[BN * STRB];

  const int tid = threadIdx.x;
  const int bn = blockIdx.x % nWGn;
  const int bm = blockIdx.x / nWGn;
  const int kp = blockIdx.y;

  const int wave = tid >> 6, lane = tid & 63;
  const int wm = wave / NWN, wn = wave % NWN;
  const int lr = lane & 15;
  const int lk = (lane >> 4) * 8;

  const long long abase = (long long)bm * BM * lda + (long long)kp * Kslice;
  const long long bbase = (long long)bn * BN * ldb + (long long)kp * Kslice;

  f32x4 acc[MF][NF];
  #pragma unroll
  for (int mi = 0; mi < MF; ++mi)
    #pragma unroll
    for (int ni = 0; ni < NF; ++ni)
      acc[mi][ni] = f32x4{0.f, 0.f, 0.f, 0.f};

  for (int k0 = 0; k0 < Kslice; k0 += BK) {
    {
      const unsigned short* Ab2 = Ap + abase + k0;
      #pragma unroll
      for (int i = 0; i < BM*BK/2048; ++i) {
        int c = i*256 + tid;
        int r = c / (BK/8);
        int kc = (c % (BK/8)) * 8;
        *(uint4v*)&lds_a[r*STRA + kc] = *(const uint4v*)(Ab2 + (long long)r*lda + kc);
      }
    }
    {
      const unsigned short* Bb2 = Bp + bbase + k0;
      #pragma unroll
      for (int i = 0; i < BN*BK/2048; ++i) {
        int c = i*256 + tid;
        int r = c / (BK/8);
        int kc = (c % (BK/8)) * 8;
        *(uint4v*)&lds_b[r*STRB + kc] = *(const uint4v*)(Bb2 + (long long)r*ldb + kc);
      }
    }
    __syncthreads();

    #pragma unroll
    for (int kk = 0; kk < BK/32; ++kk) {
      short8 af[MF]; short8 bfr[NF];
      #pragma unroll
      for (int mi = 0; mi < MF; ++mi)
        af[mi] = *(const short8*)&lds_a[(wm*WM + mi*16 + lr)*STRA + kk*32 + lk];
      #pragma unroll
      for (int ni = 0; ni < NF; ++ni)
        bfr[ni] = *(const short8*)&lds_b[(wn*WN + ni*16 + lr)*STRB + kk*32 + lk];
      #pragma unroll
      for (int mi = 0; mi < MF; ++mi)
        #pragma unroll
        for (int ni = 0; ni < NF; ++ni)
          acc[mi][ni] = __builtin_amdgcn_mfma_f32_16x16x32_bf16(af[mi], bfr[ni], acc[mi][ni], 0, 0, 0);
    }
    __syncthreads();
  }

  const int cr0 = (lane >> 4) * 4;
  #pragma unroll
  for (int mi = 0; mi < MF; ++mi) {
    #pragma unroll
    for (int ni = 0; ni < NF; ++ni) {
      int row = bm*BM + wm*WM + mi*16 + cr0;
      int col = bn*BN + wn*WN + ni*16 + lr;
      float badd = (DO_BIAS && kp == 0) ? bias[col] : 0.f;
      #pragma unroll
      for (int r = 0; r < 4; ++r) {
        float x = acc[mi][ni][r] + badd;
        unsafeAtomicAdd(&Cv[(long long)(row + r) * ldc + col], x);
      }
    }
  }
}

extern "C" void kernel_launch(void* const* d_in, const int* in_sizes, int n_in,
                              void* d_out, int out_size, void* d_ws, size_t ws_size,
                              hipStream_t stream) {
  const float* x       = (const float*)d_in[0];   // (32,512,1024)
  const float* routers = (const float*)d_in[1];   // (8,64,256)
  const float* wkv     = (const float*)d_in[2];   // (2048,1024)
  const float* projw   = (const float*)d_in[3];   // (1024,2048)
  const float* pbias   = (const float*)d_in[4];   // (1024,)

  char* ws = (char*)d_ws;
  unsigned short* wkv_b   = (unsigned short*)(ws);                //  4,194,304 B
  unsigned short* projw_b = (unsigned short*)(ws +  4194304);     //  4,194,304 B
  unsigned short* kv_b    = (unsigned short*)(ws +  8388608);     // 67,108,864 B (16384 x 2048)
  // region R: xb lives here ONLY during gemm1; ao_b reuses it afterwards.
  unsigned short* xb      = (unsigned short*)(ws + 75497472);     // 33,554,432 B (16384 x 1024)
  unsigned short* ao_b    = (unsigned short*)(ws + 92536832);     //  8,388,608 B (2048 x 2048)

  float* out0  = (float*)d_out;            // (32,64,1024)
  float* attnw = out0 + 2097152;           // (32,8,64,512) f32 softmax output

  // cast wkv | projw | x  +  zero out0 (5,767,168 float4 units)
  cast_all<<<22528, 256, 0, stream>>>(x, wkv, projw, xb, wkv_b, projw_b, out0);

  // kv = x @ wkv^T : M=16384 N=2048 K=1024 -> bf16 kv_b ; grid 64x8 = 512 wgs
  gemm1_8phase<<<512, 512, 0, stream>>>(xb, wkv_b, kv_b, 1024, 1024, 2048, 1024, 8);

  // fused S = routers@kv^T/16 + softmax -> attnw, then AO = P@kv -> ao_b; 1 wg per bh
  score_softmax_pv<<<256, 1024, 0, stream>>>(routers, kv_b, attnw, ao_b);

  // out += AO @ projw^T (+bias on kp==0) : M=2048 N=1024, K split 2x1024, atomic
  gemm_bt_splitk<64,128,64,64,32,true><<<dim3(256,2), 256, 0, stream>>>(
      ao_b, projw_b, out0, pbias, 2048, 2048, 1024, 1024, 8);
}